// Round 11
// baseline (133.836 us; speedup 1.0000x reference)
//
#include <hip/hip_runtime.h>
#include <math.h>

#define NSLOT 5
#define EPSF 1e-8f

typedef float f4 __attribute__((ext_vector_type(4)));

static __device__ __forceinline__ float d4(f4 a, f4 b) {
    return fmaf(a.x, b.x, fmaf(a.y, b.y, fmaf(a.z, b.z, a.w * b.w)));
}

// ---------------- binning kernels ----------------

__global__ void hist_kernel(const int* __restrict__ labels, int* __restrict__ counts, int B) {
    int i = blockIdx.x * blockDim.x + threadIdx.x;
    if (i < B) atomicAdd(&counts[labels[i]], 1);
}

__global__ void scan_kernel(const int* __restrict__ counts, int* __restrict__ offsets,
                            int* __restrict__ cursor, int C) {
    __shared__ int sh[1024];
    __shared__ int running;
    if (threadIdx.x == 0) running = 0;
    __syncthreads();
    for (int base = 0; base < C; base += 1024) {
        int t = base + threadIdx.x;
        int v = (t < C) ? counts[t] : 0;
        sh[threadIdx.x] = v;
        __syncthreads();
        for (int d = 1; d < 1024; d <<= 1) {
            int x = (threadIdx.x >= d) ? sh[threadIdx.x - d] : 0;
            __syncthreads();
            sh[threadIdx.x] += x;
            __syncthreads();
        }
        int excl = sh[threadIdx.x] - v + running;
        if (t < C) { offsets[t] = excl; cursor[t] = excl; }
        __syncthreads();
        if (threadIdx.x == 0) running += sh[1023];
        __syncthreads();
    }
}

__global__ void scatter_kernel(const int* __restrict__ labels, int* __restrict__ cursor,
                               int* __restrict__ bucket, int B) {
    int i = blockIdx.x * blockDim.x + threadIdx.x;
    if (i < B) {
        int slot = atomicAdd(&cursor[labels[i]], 1);
        bucket[slot] = i;
    }
}

// ---------------- class-centric, wave-parallel main kernel (D=2048) ----------------
// One block per class, 8 waves. Keys staged to LDS once (kills the 4-5x key
// re-read through L1 -- the measured ~12 B/cy/CU L1-miss path). Each WAVE then
// independently processes one sample (wave w -> samples w, w+8, ...): q + dots
// from LDS, epilogue in-wave, top-3 value rows from global (same-CU concurrent
// re-reads of the same rows -> L1 hits). No per-sample barriers.

__global__ __launch_bounds__(512, 4) void mb_class_kernel(
    const float* __restrict__ query,
    const float* __restrict__ mkeys,
    const float* __restrict__ mvals,
    const float* __restrict__ qscores,
    const int*   __restrict__ topk_p,
    const int*   __restrict__ counts,
    const int*   __restrict__ offsets,
    const int*   __restrict__ bucket,
    float* __restrict__ out_ret,
    float* __restrict__ out_w)
{
    const int c   = blockIdx.x;
    const int cnt = counts[c];
    if (cnt == 0) return;
    const int off  = offsets[c];
    const int tid  = threadIdx.x;
    const int lane = tid & 63;
    const int wave = tid >> 6;          // 0..7

    __shared__ f4 kls[NSLOT * 512];     // 40 KiB: this class's 5 key rows

    const f4* kc    = reinterpret_cast<const f4*>(mkeys) + (size_t)c * NSLOT * 512;
    const f4* vc    = reinterpret_cast<const f4*>(mvals) + (size_t)c * NSLOT * 512;
    const f4* qbase = reinterpret_cast<const f4*>(query);

    // stage keys: 512 threads x 5 contiguous f4 loads
#pragma unroll
    for (int m = 0; m < NSLOT; ++m)
        kls[tid + m * 512] = kc[tid + m * 512];

    int k = topk_p[0];
    if (k > NSLOT) k = NSLOT;
    if (k < 1) k = 1;

    float scr[NSLOT];
    float ssum = 0.f;
#pragma unroll
    for (int s = 0; s < NSLOT; ++s) {
        scr[s] = qscores[(size_t)c * NSLOT + s];
        ssum += scr[s];
    }
    const bool hit = (ssum != 0.0f);

    __syncthreads();                    // keys staged; no more block barriers

    // ---- per-wave key norms from LDS (redundant across waves, cheap) ----
    float fac[NSLOT];                   // scr[s]/kn[s]
#pragma unroll
    for (int s = 0; s < NSLOT; ++s) {
        float acc = 0.f;
#pragma unroll
        for (int m = 0; m < 8; ++m) {
            f4 t = kls[s * 512 + lane + m * 64];
            acc = fmaf(t.x, t.x, fmaf(t.y, t.y, fmaf(t.z, t.z, fmaf(t.w, t.w, acc))));
        }
#pragma unroll
        for (int o = 1; o < 64; o <<= 1) acc += __shfl_xor(acc, o);
        fac[s] = scr[s] / fmaxf(sqrtf(acc), EPSF);
    }

    // ---- wave-parallel sample loop ----
    for (int j = wave; j < cnt; j += 8) {
        const int i = bucket[off + j];
        const f4* q4 = qbase + (size_t)i * 512;

        // q chunks (8 independent global loads), then dots from LDS
        f4 qv[8];
#pragma unroll
        for (int m = 0; m < 8; ++m) qv[m] = q4[lane + m * 64];

        float qq = 0.f;
        float dot[NSLOT] = {0.f, 0.f, 0.f, 0.f, 0.f};
#pragma unroll
        for (int m = 0; m < 8; ++m) {
            f4 q = qv[m];
            qq = fmaf(q.x, q.x, fmaf(q.y, q.y, fmaf(q.z, q.z, fmaf(q.w, q.w, qq))));
#pragma unroll
            for (int s = 0; s < NSLOT; ++s) {
                f4 t = kls[s * 512 + lane + m * 64];
                dot[s] = fmaf(q.x, t.x, fmaf(q.y, t.y,
                         fmaf(q.z, t.z, fmaf(q.w, t.w, dot[s]))));
            }
        }

#pragma unroll
        for (int o = 1; o < 64; o <<= 1) {
            qq += __shfl_xor(qq, o);
#pragma unroll
            for (int s = 0; s < NSLOT; ++s) dot[s] += __shfl_xor(dot[s], o);
        }

        // ---- epilogue (all lanes redundantly) ----
        float qn = fmaxf(sqrtf(qq), EPSF);
        float comb[NSLOT];
#pragma unroll
        for (int s = 0; s < NSLOT; ++s) comb[s] = (dot[s] / qn) * fac[s];

        bool used[NSLOT];
#pragma unroll
        for (int s = 0; s < NSLOT; ++s) used[s] = false;
        float tsc[NSLOT];
        int   tix[NSLOT];
#pragma unroll
        for (int jj = 0; jj < NSLOT; ++jj) {
            float best = -INFINITY;
            int bi = 0;
            if (jj < k) {
#pragma unroll
                for (int s = 0; s < NSLOT; ++s) {
                    if (!used[s] && comb[s] > best) { best = comb[s]; bi = s; }
                }
#pragma unroll
                for (int s = 0; s < NSLOT; ++s) used[s] = used[s] || (s == bi);
            }
            tsc[jj] = best;
            tix[jj] = bi;
        }

        float m0 = tsc[0];
        float esum = 0.f, wsum = 0.f;
        float a[NSLOT];
#pragma unroll
        for (int jj = 0; jj < NSLOT; ++jj) {
            if (jj < k) {
                a[jj] = __expf((tsc[jj] - m0) * 10.0f);   // 1/TEMP = 10
                esum += a[jj];
                wsum += tsc[jj];
            } else {
                a[jj] = 0.f;
            }
        }
        float inv = hit ? (1.0f / esum) : 0.0f;

        if (lane == 0) out_w[i] = hit ? (wsum / (float)k) : 0.0f;

        // ---- pass 2: selected value rows only ----
        f4* o4 = reinterpret_cast<f4*>(out_ret) + (size_t)i * 512;
        if (k == 3) {
            const float a0 = a[0] * inv, a1 = a[1] * inv, a2 = a[2] * inv;
            const f4* p0 = vc + tix[0] * 512 + lane;
            const f4* p1 = vc + tix[1] * 512 + lane;
            const f4* p2 = vc + tix[2] * 512 + lane;
#pragma unroll
            for (int m = 0; m < 8; ++m) {
                f4 v0 = p0[m * 64];
                f4 v1 = p1[m * 64];
                f4 v2 = p2[m * 64];
                f4 acc;
                acc.x = fmaf(a0, v0.x, fmaf(a1, v1.x, a2 * v2.x));
                acc.y = fmaf(a0, v0.y, fmaf(a1, v1.y, a2 * v2.y));
                acc.z = fmaf(a0, v0.z, fmaf(a1, v1.z, a2 * v2.z));
                acc.w = fmaf(a0, v0.w, fmaf(a1, v1.w, a2 * v2.w));
                o4[lane + m * 64] = acc;
            }
        } else {
            float wgt[NSLOT];
#pragma unroll
            for (int s = 0; s < NSLOT; ++s) {
                float wsv = 0.f;
#pragma unroll
                for (int jj = 0; jj < NSLOT; ++jj)
                    if (jj < k && tix[jj] == s) wsv += a[jj] * inv;
                wgt[s] = wsv;
            }
#pragma unroll
            for (int m = 0; m < 8; ++m) {
                f4 acc = (f4)(0.f);
#pragma unroll
                for (int s = 0; s < NSLOT; ++s) {
                    f4 v = vc[s * 512 + lane + m * 64];
                    acc.x = fmaf(wgt[s], v.x, acc.x);
                    acc.y = fmaf(wgt[s], v.y, acc.y);
                    acc.z = fmaf(wgt[s], v.z, acc.z);
                    acc.w = fmaf(wgt[s], v.w, acc.w);
                }
                o4[lane + m * 64] = acc;
            }
        }
    }
}

// ---------------- generic fallback (any D), sample-centric ----------------

__global__ __launch_bounds__(64) void mb_generic_kernel(
    const float* __restrict__ query,
    const int*   __restrict__ labels,
    const float* __restrict__ mkeys,
    const float* __restrict__ mvals,
    const float* __restrict__ qscores,
    const int*   __restrict__ topk_p,
    float* __restrict__ out_ret,
    float* __restrict__ out_w,
    int B, int n4)
{
    const int lane = threadIdx.x;
    const int i    = blockIdx.x;
    if (i >= B) return;
    const int c = labels[i];
    int k = topk_p[0];
    if (k > NSLOT) k = NSLOT;
    if (k < 1) k = 1;

    const f4* q4 = reinterpret_cast<const f4*>(query) + (size_t)i * n4;
    const f4* k4 = reinterpret_cast<const f4*>(mkeys) + (size_t)c * NSLOT * n4;
    const f4* v4 = reinterpret_cast<const f4*>(mvals) + (size_t)c * NSLOT * n4;
    f4*       o4 = reinterpret_cast<f4*>(out_ret) + (size_t)i * n4;

    float qq = 0.f, dot[NSLOT] = {0}, kk[NSLOT] = {0};
    for (int idx = lane; idx < n4; idx += 64) {
        f4 q = q4[idx];
        qq += d4(q, q);
        for (int s = 0; s < NSLOT; ++s) {
            f4 t = k4[s * n4 + idx];
            dot[s] += d4(q, t);
            kk[s]  += d4(t, t);
        }
    }
    for (int o = 1; o < 64; o <<= 1) {
        qq += __shfl_xor(qq, o);
        for (int s = 0; s < NSLOT; ++s) {
            dot[s] += __shfl_xor(dot[s], o);
            kk[s]  += __shfl_xor(kk[s], o);
        }
    }
    float qn = fmaxf(sqrtf(qq), EPSF);
    float scr[NSLOT], ssum = 0.f;
    for (int s = 0; s < NSLOT; ++s) { scr[s] = qscores[(size_t)c * NSLOT + s]; ssum += scr[s]; }
    float comb[NSLOT];
    for (int s = 0; s < NSLOT; ++s)
        comb[s] = (dot[s] / (qn * fmaxf(sqrtf(kk[s]), EPSF))) * scr[s];
    bool used[NSLOT] = {false, false, false, false, false};
    float tsc[NSLOT]; int tix[NSLOT];
    for (int jj = 0; jj < NSLOT; ++jj) {
        float best = -INFINITY; int bi = 0;
        if (jj < k) {
            for (int s = 0; s < NSLOT; ++s)
                if (!used[s] && comb[s] > best) { best = comb[s]; bi = s; }
            used[bi] = true;
        }
        tsc[jj] = best; tix[jj] = bi;
    }
    const bool hit = (ssum != 0.0f);
    float m = tsc[0], esum = 0.f, wsum = 0.f, a[NSLOT];
    for (int jj = 0; jj < NSLOT; ++jj) {
        if (jj < k) { a[jj] = __expf((tsc[jj] - m) * 10.0f); esum += a[jj]; wsum += tsc[jj]; }
        else a[jj] = 0.f;
    }
    float inv = hit ? (1.0f / esum) : 0.0f;
    float w[NSLOT];
    for (int s = 0; s < NSLOT; ++s) {
        float wsv = 0.f;
        for (int jj = 0; jj < NSLOT; ++jj) if (jj < k && tix[jj] == s) wsv += a[jj] * inv;
        w[s] = wsv;
    }
    if (lane == 0) out_w[i] = hit ? (wsum / (float)k) : 0.0f;
    for (int idx = lane; idx < n4; idx += 64) {
        f4 acc = (f4)(0.f);
        for (int s = 0; s < NSLOT; ++s) {
            f4 v = v4[s * n4 + idx];
            acc += v * w[s];
        }
        o4[idx] = acc;
    }
}

extern "C" void kernel_launch(void* const* d_in, const int* in_sizes, int n_in,
                              void* d_out, int out_size, void* d_ws, size_t ws_size,
                              hipStream_t stream) {
    const float* query   = (const float*)d_in[0];
    const int*   labels  = (const int*)d_in[1];
    const float* mkeys   = (const float*)d_in[2];
    const float* mvals   = (const float*)d_in[3];
    const float* qscores = (const float*)d_in[4];
    const int*   topk    = (const int*)d_in[5];

    const int B  = in_sizes[1];
    const int D  = in_sizes[0] / B;
    const int n4 = D >> 2;
    const int C  = in_sizes[4] / NSLOT;

    float* out_ret = (float*)d_out;
    float* out_w   = out_ret + (size_t)B * D;

    if (D == 2048 && ((size_t)(3 * C + B) * sizeof(int) <= ws_size)) {
        int* counts  = (int*)d_ws;
        int* offsets = counts + C;
        int* cursor  = offsets + C;
        int* bkt     = cursor + C;
        hipMemsetAsync(counts, 0, (size_t)C * sizeof(int), stream);
        hist_kernel<<<dim3((B + 255) / 256), dim3(256), 0, stream>>>(labels, counts, B);
        scan_kernel<<<dim3(1), dim3(1024), 0, stream>>>(counts, offsets, cursor, C);
        scatter_kernel<<<dim3((B + 255) / 256), dim3(256), 0, stream>>>(labels, cursor, bkt, B);

        mb_class_kernel<<<dim3(C), dim3(512), 0, stream>>>(
            query, mkeys, mvals, qscores, topk, counts, offsets, bkt, out_ret, out_w);
    } else {
        mb_generic_kernel<<<dim3(B), dim3(64), 0, stream>>>(
            query, labels, mkeys, mvals, qscores, topk, out_ret, out_w, B, n4);
    }
}

// Round 12
// 92.189 us; speedup vs baseline: 1.4517x; 1.4517x over previous
//
#include <hip/hip_runtime.h>
#include <math.h>

#define NSLOT 5
#define EPSF 1e-8f

typedef float f4 __attribute__((ext_vector_type(4)));

static __device__ __forceinline__ float d4(f4 a, f4 b) {
    return fmaf(a.x, b.x, fmaf(a.y, b.y, fmaf(a.z, b.z, a.w * b.w)));
}

// ---------------- binning kernels ----------------

__global__ void hist_kernel(const int* __restrict__ labels, int* __restrict__ counts, int B) {
    int i = blockIdx.x * blockDim.x + threadIdx.x;
    if (i < B) atomicAdd(&counts[labels[i]], 1);
}

__global__ void scan_kernel(const int* __restrict__ counts, int* __restrict__ offsets,
                            int* __restrict__ cursor, int C) {
    __shared__ int sh[1024];
    __shared__ int running;
    if (threadIdx.x == 0) running = 0;
    __syncthreads();
    for (int base = 0; base < C; base += 1024) {
        int t = base + threadIdx.x;
        int v = (t < C) ? counts[t] : 0;
        sh[threadIdx.x] = v;
        __syncthreads();
        for (int d = 1; d < 1024; d <<= 1) {
            int x = (threadIdx.x >= d) ? sh[threadIdx.x - d] : 0;
            __syncthreads();
            sh[threadIdx.x] += x;
            __syncthreads();
        }
        int excl = sh[threadIdx.x] - v + running;
        if (t < C) { offsets[t] = excl; cursor[t] = excl; }
        __syncthreads();
        if (threadIdx.x == 0) running += sh[1023];
        __syncthreads();
    }
}

__global__ void scatter_kernel(const int* __restrict__ labels, int* __restrict__ cursor,
                               int* __restrict__ bucket, int B) {
    int i = blockIdx.x * blockDim.x + threadIdx.x;
    if (i < B) {
        int slot = atomicAdd(&cursor[labels[i]], 1);
        bucket[slot] = i;
    }
}

// ---------------- class-centric, wave-parallel, keys+vals in LDS ----------------
// One block per class, 8 waves. Keys AND values staged to LDS once per class:
// global traffic collapses to q (33.5 MB) + keys (41) + vals (41) + out (33.5).
// Each wave independently processes one sample; no per-sample barriers.
// Resource discipline (R6/R11 lessons): no per-thread f4 arrays; 80 KB LDS ->
// 2 blocks/CU -> 4 waves/SIMD -> VGPR must be <=128 (launch_bounds min 4/EU).

__global__ __launch_bounds__(512, 4) void mb_class_kernel(
    const float* __restrict__ query,
    const float* __restrict__ mkeys,
    const float* __restrict__ mvals,
    const float* __restrict__ qscores,
    const int*   __restrict__ topk_p,
    const int*   __restrict__ counts,
    const int*   __restrict__ offsets,
    const int*   __restrict__ bucket,
    float* __restrict__ out_ret,
    float* __restrict__ out_w)
{
    const int c   = blockIdx.x;
    const int cnt = counts[c];
    if (cnt == 0) return;
    const int off  = offsets[c];
    const int tid  = threadIdx.x;
    const int lane = tid & 63;
    const int wave = tid >> 6;          // 0..7

    __shared__ f4 kls[NSLOT * 512];     // 40 KiB keys
    __shared__ f4 vls[NSLOT * 512];     // 40 KiB values

    const f4* kc    = reinterpret_cast<const f4*>(mkeys) + (size_t)c * NSLOT * 512;
    const f4* vc    = reinterpret_cast<const f4*>(mvals) + (size_t)c * NSLOT * 512;
    const f4* qbase = reinterpret_cast<const f4*>(query);

    // stage keys + vals: 10 contiguous f4 loads per thread
#pragma unroll
    for (int m = 0; m < NSLOT; ++m) {
        kls[tid + m * 512] = kc[tid + m * 512];
        vls[tid + m * 512] = vc[tid + m * 512];
    }

    int k = topk_p[0];
    if (k > NSLOT) k = NSLOT;
    if (k < 1) k = 1;

    float scr[NSLOT];
    float ssum = 0.f;
#pragma unroll
    for (int s = 0; s < NSLOT; ++s) {
        scr[s] = qscores[(size_t)c * NSLOT + s];
        ssum += scr[s];
    }
    const bool hit = (ssum != 0.0f);

    __syncthreads();                    // staging done; no more block barriers

    // ---- per-wave key norms from LDS (redundant across waves, cheap) ----
    float fac[NSLOT];                   // scr[s]/kn[s]
#pragma unroll
    for (int s = 0; s < NSLOT; ++s) {
        float acc = 0.f;
#pragma unroll
        for (int m = 0; m < 8; ++m) {
            f4 t = kls[s * 512 + lane + m * 64];
            acc = fmaf(t.x, t.x, fmaf(t.y, t.y, fmaf(t.z, t.z, fmaf(t.w, t.w, acc))));
        }
#pragma unroll
        for (int o = 1; o < 64; o <<= 1) acc += __shfl_xor(acc, o);
        fac[s] = scr[s] / fmaxf(sqrtf(acc), EPSF);
    }

    // ---- wave-parallel sample loop ----
    for (int j = wave; j < cnt; j += 8) {
        const int i = bucket[off + j];
        const f4* q4 = qbase + (size_t)i * 512 + lane;

        float qq = 0.f;
        float dot[NSLOT] = {0.f, 0.f, 0.f, 0.f, 0.f};
#pragma unroll
        for (int m = 0; m < 8; ++m) {
            f4 q = q4[m * 64];
            qq = fmaf(q.x, q.x, fmaf(q.y, q.y, fmaf(q.z, q.z, fmaf(q.w, q.w, qq))));
#pragma unroll
            for (int s = 0; s < NSLOT; ++s) {
                f4 t = kls[s * 512 + lane + m * 64];
                dot[s] = fmaf(q.x, t.x, fmaf(q.y, t.y,
                         fmaf(q.z, t.z, fmaf(q.w, t.w, dot[s]))));
            }
        }

#pragma unroll
        for (int o = 1; o < 64; o <<= 1) {
            qq += __shfl_xor(qq, o);
#pragma unroll
            for (int s = 0; s < NSLOT; ++s) dot[s] += __shfl_xor(dot[s], o);
        }

        // ---- epilogue (all lanes redundantly) ----
        float qn = fmaxf(sqrtf(qq), EPSF);
        float comb[NSLOT];
#pragma unroll
        for (int s = 0; s < NSLOT; ++s) comb[s] = (dot[s] / qn) * fac[s];

        bool used[NSLOT];
#pragma unroll
        for (int s = 0; s < NSLOT; ++s) used[s] = false;
        float tsc[NSLOT];
        int   tix[NSLOT];
#pragma unroll
        for (int jj = 0; jj < NSLOT; ++jj) {
            float best = -INFINITY;
            int bi = 0;
            if (jj < k) {
#pragma unroll
                for (int s = 0; s < NSLOT; ++s) {
                    if (!used[s] && comb[s] > best) { best = comb[s]; bi = s; }
                }
#pragma unroll
                for (int s = 0; s < NSLOT; ++s) used[s] = used[s] || (s == bi);
            }
            tsc[jj] = best;
            tix[jj] = bi;
        }

        float m0 = tsc[0];
        float esum = 0.f, wsum = 0.f;
        float a[NSLOT];
#pragma unroll
        for (int jj = 0; jj < NSLOT; ++jj) {
            if (jj < k) {
                a[jj] = __expf((tsc[jj] - m0) * 10.0f);   // 1/TEMP = 10
                esum += a[jj];
                wsum += tsc[jj];
            } else {
                a[jj] = 0.f;
            }
        }
        float inv = hit ? (1.0f / esum) : 0.0f;

        if (lane == 0) out_w[i] = hit ? (wsum / (float)k) : 0.0f;

        // ---- pass 2: selected rows from LDS, only stores go global ----
        f4* o4 = reinterpret_cast<f4*>(out_ret) + (size_t)i * 512 + lane;
        if (k == 3) {
            const float a0 = a[0] * inv, a1 = a[1] * inv, a2 = a[2] * inv;
            const int b0 = tix[0] * 512 + lane;
            const int b1 = tix[1] * 512 + lane;
            const int b2 = tix[2] * 512 + lane;
#pragma unroll
            for (int m = 0; m < 8; ++m) {
                f4 v0 = vls[b0 + m * 64];
                f4 v1 = vls[b1 + m * 64];
                f4 v2 = vls[b2 + m * 64];
                f4 acc;
                acc.x = fmaf(a0, v0.x, fmaf(a1, v1.x, a2 * v2.x));
                acc.y = fmaf(a0, v0.y, fmaf(a1, v1.y, a2 * v2.y));
                acc.z = fmaf(a0, v0.z, fmaf(a1, v1.z, a2 * v2.z));
                acc.w = fmaf(a0, v0.w, fmaf(a1, v1.w, a2 * v2.w));
                o4[m * 64] = acc;
            }
        } else {
            float wgt[NSLOT];
#pragma unroll
            for (int s = 0; s < NSLOT; ++s) {
                float wsv = 0.f;
#pragma unroll
                for (int jj = 0; jj < NSLOT; ++jj)
                    if (jj < k && tix[jj] == s) wsv += a[jj] * inv;
                wgt[s] = wsv;
            }
#pragma unroll
            for (int m = 0; m < 8; ++m) {
                f4 acc = (f4)(0.f);
#pragma unroll
                for (int s = 0; s < NSLOT; ++s) {
                    f4 v = vls[s * 512 + lane + m * 64];
                    acc.x = fmaf(wgt[s], v.x, acc.x);
                    acc.y = fmaf(wgt[s], v.y, acc.y);
                    acc.z = fmaf(wgt[s], v.z, acc.z);
                    acc.w = fmaf(wgt[s], v.w, acc.w);
                }
                o4[m * 64] = acc;
            }
        }
    }
}

// ---------------- generic fallback (any D), sample-centric ----------------

__global__ __launch_bounds__(64) void mb_generic_kernel(
    const float* __restrict__ query,
    const int*   __restrict__ labels,
    const float* __restrict__ mkeys,
    const float* __restrict__ mvals,
    const float* __restrict__ qscores,
    const int*   __restrict__ topk_p,
    float* __restrict__ out_ret,
    float* __restrict__ out_w,
    int B, int n4)
{
    const int lane = threadIdx.x;
    const int i    = blockIdx.x;
    if (i >= B) return;
    const int c = labels[i];
    int k = topk_p[0];
    if (k > NSLOT) k = NSLOT;
    if (k < 1) k = 1;

    const f4* q4 = reinterpret_cast<const f4*>(query) + (size_t)i * n4;
    const f4* k4 = reinterpret_cast<const f4*>(mkeys) + (size_t)c * NSLOT * n4;
    const f4* v4 = reinterpret_cast<const f4*>(mvals) + (size_t)c * NSLOT * n4;
    f4*       o4 = reinterpret_cast<f4*>(out_ret) + (size_t)i * n4;

    float qq = 0.f, dot[NSLOT] = {0}, kk[NSLOT] = {0};
    for (int idx = lane; idx < n4; idx += 64) {
        f4 q = q4[idx];
        qq += d4(q, q);
        for (int s = 0; s < NSLOT; ++s) {
            f4 t = k4[s * n4 + idx];
            dot[s] += d4(q, t);
            kk[s]  += d4(t, t);
        }
    }
    for (int o = 1; o < 64; o <<= 1) {
        qq += __shfl_xor(qq, o);
        for (int s = 0; s < NSLOT; ++s) {
            dot[s] += __shfl_xor(dot[s], o);
            kk[s]  += __shfl_xor(kk[s], o);
        }
    }
    float qn = fmaxf(sqrtf(qq), EPSF);
    float scr[NSLOT], ssum = 0.f;
    for (int s = 0; s < NSLOT; ++s) { scr[s] = qscores[(size_t)c * NSLOT + s]; ssum += scr[s]; }
    float comb[NSLOT];
    for (int s = 0; s < NSLOT; ++s)
        comb[s] = (dot[s] / (qn * fmaxf(sqrtf(kk[s]), EPSF))) * scr[s];
    bool used[NSLOT] = {false, false, false, false, false};
    float tsc[NSLOT]; int tix[NSLOT];
    for (int jj = 0; jj < NSLOT; ++jj) {
        float best = -INFINITY; int bi = 0;
        if (jj < k) {
            for (int s = 0; s < NSLOT; ++s)
                if (!used[s] && comb[s] > best) { best = comb[s]; bi = s; }
            used[bi] = true;
        }
        tsc[jj] = best; tix[jj] = bi;
    }
    const bool hit = (ssum != 0.0f);
    float m = tsc[0], esum = 0.f, wsum = 0.f, a[NSLOT];
    for (int jj = 0; jj < NSLOT; ++jj) {
        if (jj < k) { a[jj] = __expf((tsc[jj] - m) * 10.0f); esum += a[jj]; wsum += tsc[jj]; }
        else a[jj] = 0.f;
    }
    float inv = hit ? (1.0f / esum) : 0.0f;
    float w[NSLOT];
    for (int s = 0; s < NSLOT; ++s) {
        float wsv = 0.f;
        for (int jj = 0; jj < NSLOT; ++jj) if (jj < k && tix[jj] == s) wsv += a[jj] * inv;
        w[s] = wsv;
    }
    if (lane == 0) out_w[i] = hit ? (wsum / (float)k) : 0.0f;
    for (int idx = lane; idx < n4; idx += 64) {
        f4 acc = (f4)(0.f);
        for (int s = 0; s < NSLOT; ++s) {
            f4 v = v4[s * n4 + idx];
            acc += v * w[s];
        }
        o4[idx] = acc;
    }
}

extern "C" void kernel_launch(void* const* d_in, const int* in_sizes, int n_in,
                              void* d_out, int out_size, void* d_ws, size_t ws_size,
                              hipStream_t stream) {
    const float* query   = (const float*)d_in[0];
    const int*   labels  = (const int*)d_in[1];
    const float* mkeys   = (const float*)d_in[2];
    const float* mvals   = (const float*)d_in[3];
    const float* qscores = (const float*)d_in[4];
    const int*   topk    = (const int*)d_in[5];

    const int B  = in_sizes[1];
    const int D  = in_sizes[0] / B;
    const int n4 = D >> 2;
    const int C  = in_sizes[4] / NSLOT;

    float* out_ret = (float*)d_out;
    float* out_w   = out_ret + (size_t)B * D;

    if (D == 2048 && ((size_t)(3 * C + B) * sizeof(int) <= ws_size)) {
        int* counts  = (int*)d_ws;
        int* offsets = counts + C;
        int* cursor  = offsets + C;
        int* bkt     = cursor + C;
        hipMemsetAsync(counts, 0, (size_t)C * sizeof(int), stream);
        hist_kernel<<<dim3((B + 255) / 256), dim3(256), 0, stream>>>(labels, counts, B);
        scan_kernel<<<dim3(1), dim3(1024), 0, stream>>>(counts, offsets, cursor, C);
        scatter_kernel<<<dim3((B + 255) / 256), dim3(256), 0, stream>>>(labels, cursor, bkt, B);

        mb_class_kernel<<<dim3(C), dim3(512), 0, stream>>>(
            query, mkeys, mvals, qscores, topk, counts, offsets, bkt, out_ret, out_w);
    } else {
        mb_generic_kernel<<<dim3(B), dim3(64), 0, stream>>>(
            query, labels, mkeys, mvals, qscores, topk, out_ret, out_w, B, n4);
    }
}

// Round 13
// 60.469 us; speedup vs baseline: 2.2133x; 1.5246x over previous
//
#include <hip/hip_runtime.h>
#include <math.h>

#define NSLOT 5
#define EPSF 1e-8f
#define TG 4   // samples per wave-task

typedef float f4 __attribute__((ext_vector_type(4)));

static __device__ __forceinline__ float d4(f4 a, f4 b) {
    return fmaf(a.x, b.x, fmaf(a.y, b.y, fmaf(a.z, b.z, a.w * b.w)));
}

// ---------------- binning kernels ----------------

__global__ void hist_kernel(const int* __restrict__ labels, int* __restrict__ counts, int B) {
    int i = blockIdx.x * blockDim.x + threadIdx.x;
    if (i < B) atomicAdd(&counts[labels[i]], 1);
}

// exclusive scan of counts -> offsets & cursor
__global__ void scan_kernel(const int* __restrict__ counts, int* __restrict__ offsets,
                            int* __restrict__ cursor, int C) {
    __shared__ int sh[1024];
    __shared__ int running;
    if (threadIdx.x == 0) running = 0;
    __syncthreads();
    for (int base = 0; base < C; base += 1024) {
        int t = base + threadIdx.x;
        int v = (t < C) ? counts[t] : 0;
        sh[threadIdx.x] = v;
        __syncthreads();
        for (int d = 1; d < 1024; d <<= 1) {
            int x = (threadIdx.x >= d) ? sh[threadIdx.x - d] : 0;
            __syncthreads();
            sh[threadIdx.x] += x;
            __syncthreads();
        }
        int excl = sh[threadIdx.x] - v + running;
        if (t < C) { offsets[t] = excl; cursor[t] = excl; }
        __syncthreads();
        if (threadIdx.x == 0) running += sh[1023];
        __syncthreads();
    }
}

// exclusive scan of ceil(counts/TG) -> toff; total task count -> nt[0]
__global__ void scan_tasks_kernel(const int* __restrict__ counts, int* __restrict__ toff,
                                  int* __restrict__ nt, int C) {
    __shared__ int sh[1024];
    __shared__ int running;
    if (threadIdx.x == 0) running = 0;
    __syncthreads();
    for (int base = 0; base < C; base += 1024) {
        int t = base + threadIdx.x;
        int v = (t < C) ? ((counts[t] + TG - 1) / TG) : 0;
        sh[threadIdx.x] = v;
        __syncthreads();
        for (int d = 1; d < 1024; d <<= 1) {
            int x = (threadIdx.x >= d) ? sh[threadIdx.x - d] : 0;
            __syncthreads();
            sh[threadIdx.x] += x;
            __syncthreads();
        }
        int excl = sh[threadIdx.x] - v + running;
        if (t < C) toff[t] = excl;
        __syncthreads();
        if (threadIdx.x == 0) running += sh[1023];
        __syncthreads();
    }
    if (threadIdx.x == 0) nt[0] = running;
}

__global__ void scatter_kernel(const int* __restrict__ labels, int* __restrict__ cursor,
                               int* __restrict__ bucket, int B) {
    int i = blockIdx.x * blockDim.x + threadIdx.x;
    if (i < B) {
        int slot = atomicAdd(&cursor[labels[i]], 1);
        bucket[slot] = i;
    }
}

// per class: emit its tiles (deterministic order via toff)
__global__ void fill_tasks_kernel(const int* __restrict__ counts, const int* __restrict__ offsets,
                                  const int* __restrict__ toff,
                                  int* __restrict__ task_c, int* __restrict__ task_j0, int C) {
    int c = blockIdx.x * blockDim.x + threadIdx.x;
    if (c >= C) return;
    int cnt = counts[c];
    int ntc = (cnt + TG - 1) / TG;
    int tb  = toff[c];
    int off = offsets[c];
    for (int t = 0; t < ntc; ++t) {
        task_c[tb + t]  = c;
        task_j0[tb + t] = off + t * TG;
    }
}

// ---------------- main kernel: one wave per task (<=4 same-class samples) ----------------
// The wave loads each key/value chunk ONCE and applies it to all 4 samples
// (register mini-GEMM dot[4][5]). Key norms shared (same class). No LDS,
// no barriers; independent waves -> good occupancy. Block's 4 waves take 4
// consecutive tasks -> a class's tiles stay on one CU (L1 reuse).

__global__ __launch_bounds__(256, 4) void mb_task_kernel(
    const float* __restrict__ query,
    const float* __restrict__ mkeys,
    const float* __restrict__ mvals,
    const float* __restrict__ qscores,
    const int*   __restrict__ topk_p,
    const int*   __restrict__ counts,
    const int*   __restrict__ offsets,
    const int*   __restrict__ bucket,
    const int*   __restrict__ task_c,
    const int*   __restrict__ task_j0,
    const int*   __restrict__ nt_p,
    float* __restrict__ out_ret,
    float* __restrict__ out_w)
{
    const int lane = threadIdx.x & 63;
    const int wave = threadIdx.x >> 6;
    const int task = blockIdx.x * 4 + wave;
    if (task >= nt_p[0]) return;

    const int c  = task_c[task];
    const int j0 = task_j0[task];
    const int g  = min(TG, offsets[c] + counts[c] - j0);

    int k = topk_p[0];
    if (k > NSLOT) k = NSLOT;
    if (k < 1) k = 1;

    int idx[TG];
#pragma unroll
    for (int t = 0; t < TG; ++t)
        idx[t] = bucket[j0 + (t < g ? t : g - 1)];   // replicate last when short

    const f4* kp = reinterpret_cast<const f4*>(mkeys) + (size_t)c * NSLOT * 512 + lane;
    const f4* vp = reinterpret_cast<const f4*>(mvals) + (size_t)c * NSLOT * 512 + lane;
    const f4* qb = reinterpret_cast<const f4*>(query);

    // ---- pass 1: dot[t][s], qq[t], kk[s]; keys read ONCE per tile ----
    float qq[TG] = {0.f, 0.f, 0.f, 0.f};
    float kk[NSLOT] = {0.f, 0.f, 0.f, 0.f, 0.f};
    float dot[TG][NSLOT];
#pragma unroll
    for (int t = 0; t < TG; ++t)
#pragma unroll
        for (int s = 0; s < NSLOT; ++s) dot[t][s] = 0.f;

#pragma unroll
    for (int m = 0; m < 8; ++m) {
        f4 q[TG];
#pragma unroll
        for (int t = 0; t < TG; ++t) {
            q[t] = qb[(size_t)idx[t] * 512 + lane + m * 64];
            qq[t] = fmaf(q[t].x, q[t].x, fmaf(q[t].y, q[t].y,
                    fmaf(q[t].z, q[t].z, fmaf(q[t].w, q[t].w, qq[t]))));
        }
#pragma unroll
        for (int s = 0; s < NSLOT; ++s) {
            f4 kv = kp[s * 512 + m * 64];
            kk[s] = fmaf(kv.x, kv.x, fmaf(kv.y, kv.y,
                    fmaf(kv.z, kv.z, fmaf(kv.w, kv.w, kk[s]))));
#pragma unroll
            for (int t = 0; t < TG; ++t) {
                dot[t][s] = fmaf(q[t].x, kv.x, fmaf(q[t].y, kv.y,
                            fmaf(q[t].z, kv.z, fmaf(q[t].w, kv.w, dot[t][s]))));
            }
        }
    }

    // ---- butterfly reduce (29 values) ----
#pragma unroll
    for (int o = 1; o < 64; o <<= 1) {
#pragma unroll
        for (int t = 0; t < TG; ++t) {
            qq[t] += __shfl_xor(qq[t], o);
#pragma unroll
            for (int s = 0; s < NSLOT; ++s) dot[t][s] += __shfl_xor(dot[t][s], o);
        }
#pragma unroll
        for (int s = 0; s < NSLOT; ++s) kk[s] += __shfl_xor(kk[s], o);
    }

    // ---- class-shared epilogue pieces ----
    float scr[NSLOT];
    float ssum = 0.f;
#pragma unroll
    for (int s = 0; s < NSLOT; ++s) {
        scr[s] = qscores[(size_t)c * NSLOT + s];
        ssum += scr[s];
    }
    const bool hit = (ssum != 0.0f);

    float fac[NSLOT];
#pragma unroll
    for (int s = 0; s < NSLOT; ++s)
        fac[s] = scr[s] / fmaxf(sqrtf(kk[s]), EPSF);

    // ---- per-sample epilogue -> wgt[t][s] ----
    float wgt[TG][NSLOT];
#pragma unroll
    for (int t = 0; t < TG; ++t) {
        float qn = fmaxf(sqrtf(qq[t]), EPSF);
        float comb[NSLOT];
#pragma unroll
        for (int s = 0; s < NSLOT; ++s) comb[s] = (dot[t][s] / qn) * fac[s];

        bool used[NSLOT];
#pragma unroll
        for (int s = 0; s < NSLOT; ++s) used[s] = false;
        float tsc[NSLOT];
        int   tix[NSLOT];
#pragma unroll
        for (int jj = 0; jj < NSLOT; ++jj) {
            float best = -INFINITY;
            int bi = 0;
            if (jj < k) {
#pragma unroll
                for (int s = 0; s < NSLOT; ++s) {
                    if (!used[s] && comb[s] > best) { best = comb[s]; bi = s; }
                }
#pragma unroll
                for (int s = 0; s < NSLOT; ++s) used[s] = used[s] || (s == bi);
            }
            tsc[jj] = best;
            tix[jj] = bi;
        }

        float m0 = tsc[0];
        float esum = 0.f, wsum = 0.f;
        float a[NSLOT];
#pragma unroll
        for (int jj = 0; jj < NSLOT; ++jj) {
            if (jj < k) {
                a[jj] = __expf((tsc[jj] - m0) * 10.0f);   // 1/TEMP = 10
                esum += a[jj];
                wsum += tsc[jj];
            } else {
                a[jj] = 0.f;
            }
        }
        float inv = hit ? (1.0f / esum) : 0.0f;
#pragma unroll
        for (int s = 0; s < NSLOT; ++s) {
            float wsv = 0.f;
#pragma unroll
            for (int jj = 0; jj < NSLOT; ++jj)
                if (jj < k && tix[jj] == s) wsv += a[jj] * inv;
            wgt[t][s] = wsv;
        }

        if (lane == 0 && t < g) out_w[idx[t]] = hit ? (wsum / (float)k) : 0.0f;
    }

    // ---- pass 2: values read ONCE per tile, applied to all samples ----
#pragma unroll
    for (int m = 0; m < 8; ++m) {
        f4 v[NSLOT];
#pragma unroll
        for (int s = 0; s < NSLOT; ++s) v[s] = vp[s * 512 + m * 64];
#pragma unroll
        for (int t = 0; t < TG; ++t) {
            if (t < g) {
                f4 acc = (f4)(0.f);
#pragma unroll
                for (int s = 0; s < NSLOT; ++s) {
                    acc.x = fmaf(wgt[t][s], v[s].x, acc.x);
                    acc.y = fmaf(wgt[t][s], v[s].y, acc.y);
                    acc.z = fmaf(wgt[t][s], v[s].z, acc.z);
                    acc.w = fmaf(wgt[t][s], v[s].w, acc.w);
                }
                reinterpret_cast<f4*>(out_ret)[(size_t)idx[t] * 512 + lane + m * 64] = acc;
            }
        }
    }
}

// ---------------- generic fallback (any D), sample-centric ----------------

__global__ __launch_bounds__(64) void mb_generic_kernel(
    const float* __restrict__ query,
    const int*   __restrict__ labels,
    const float* __restrict__ mkeys,
    const float* __restrict__ mvals,
    const float* __restrict__ qscores,
    const int*   __restrict__ topk_p,
    float* __restrict__ out_ret,
    float* __restrict__ out_w,
    int B, int n4)
{
    const int lane = threadIdx.x;
    const int i    = blockIdx.x;
    if (i >= B) return;
    const int c = labels[i];
    int k = topk_p[0];
    if (k > NSLOT) k = NSLOT;
    if (k < 1) k = 1;

    const f4* q4 = reinterpret_cast<const f4*>(query) + (size_t)i * n4;
    const f4* k4 = reinterpret_cast<const f4*>(mkeys) + (size_t)c * NSLOT * n4;
    const f4* v4 = reinterpret_cast<const f4*>(mvals) + (size_t)c * NSLOT * n4;
    f4*       o4 = reinterpret_cast<f4*>(out_ret) + (size_t)i * n4;

    float qq = 0.f, dot[NSLOT] = {0}, kk[NSLOT] = {0};
    for (int idx = lane; idx < n4; idx += 64) {
        f4 q = q4[idx];
        qq += d4(q, q);
        for (int s = 0; s < NSLOT; ++s) {
            f4 t = k4[s * n4 + idx];
            dot[s] += d4(q, t);
            kk[s]  += d4(t, t);
        }
    }
    for (int o = 1; o < 64; o <<= 1) {
        qq += __shfl_xor(qq, o);
        for (int s = 0; s < NSLOT; ++s) {
            dot[s] += __shfl_xor(dot[s], o);
            kk[s]  += __shfl_xor(kk[s], o);
        }
    }
    float qn = fmaxf(sqrtf(qq), EPSF);
    float scr[NSLOT], ssum = 0.f;
    for (int s = 0; s < NSLOT; ++s) { scr[s] = qscores[(size_t)c * NSLOT + s]; ssum += scr[s]; }
    float comb[NSLOT];
    for (int s = 0; s < NSLOT; ++s)
        comb[s] = (dot[s] / (qn * fmaxf(sqrtf(kk[s]), EPSF))) * scr[s];
    bool used[NSLOT] = {false, false, false, false, false};
    float tsc[NSLOT]; int tix[NSLOT];
    for (int jj = 0; jj < NSLOT; ++jj) {
        float best = -INFINITY; int bi = 0;
        if (jj < k) {
            for (int s = 0; s < NSLOT; ++s)
                if (!used[s] && comb[s] > best) { best = comb[s]; bi = s; }
            used[bi] = true;
        }
        tsc[jj] = best; tix[jj] = bi;
    }
    const bool hit = (ssum != 0.0f);
    float m = tsc[0], esum = 0.f, wsum = 0.f, a[NSLOT];
    for (int jj = 0; jj < NSLOT; ++jj) {
        if (jj < k) { a[jj] = __expf((tsc[jj] - m) * 10.0f); esum += a[jj]; wsum += tsc[jj]; }
        else a[jj] = 0.f;
    }
    float inv = hit ? (1.0f / esum) : 0.0f;
    float w[NSLOT];
    for (int s = 0; s < NSLOT; ++s) {
        float wsv = 0.f;
        for (int jj = 0; jj < NSLOT; ++jj) if (jj < k && tix[jj] == s) wsv += a[jj] * inv;
        w[s] = wsv;
    }
    if (lane == 0) out_w[i] = hit ? (wsum / (float)k) : 0.0f;
    for (int idx = lane; idx < n4; idx += 64) {
        f4 acc = (f4)(0.f);
        for (int s = 0; s < NSLOT; ++s) {
            f4 v = v4[s * n4 + idx];
            acc += v * w[s];
        }
        o4[idx] = acc;
    }
}

extern "C" void kernel_launch(void* const* d_in, const int* in_sizes, int n_in,
                              void* d_out, int out_size, void* d_ws, size_t ws_size,
                              hipStream_t stream) {
    const float* query   = (const float*)d_in[0];
    const int*   labels  = (const int*)d_in[1];
    const float* mkeys   = (const float*)d_in[2];
    const float* mvals   = (const float*)d_in[3];
    const float* qscores = (const float*)d_in[4];
    const int*   topk    = (const int*)d_in[5];

    const int B  = in_sizes[1];
    const int D  = in_sizes[0] / B;
    const int n4 = D >> 2;
    const int C  = in_sizes[4] / NSLOT;

    float* out_ret = (float*)d_out;
    float* out_w   = out_ret + (size_t)B * D;

    const int TMAX = (B + (TG - 1) * C) / TG + 8;   // sum ceil(cnt/TG) bound
    const size_t need = (size_t)(4 * C + B + 1 + 2 * TMAX) * sizeof(int);

    if (D == 2048 && need <= ws_size) {
        int* counts  = (int*)d_ws;          // C
        int* offsets = counts + C;          // C
        int* cursor  = offsets + C;         // C
        int* toff    = cursor + C;          // C
        int* nt      = toff + C;            // 1
        int* bucket  = nt + 1;              // B
        int* task_c  = bucket + B;          // TMAX
        int* task_j0 = task_c + TMAX;       // TMAX

        hipMemsetAsync(counts, 0, (size_t)C * sizeof(int), stream);
        hist_kernel<<<dim3((B + 255) / 256), dim3(256), 0, stream>>>(labels, counts, B);
        scan_kernel<<<dim3(1), dim3(1024), 0, stream>>>(counts, offsets, cursor, C);
        scan_tasks_kernel<<<dim3(1), dim3(1024), 0, stream>>>(counts, toff, nt, C);
        scatter_kernel<<<dim3((B + 255) / 256), dim3(256), 0, stream>>>(labels, cursor, bucket, B);
        fill_tasks_kernel<<<dim3((C + 255) / 256), dim3(256), 0, stream>>>(
            counts, offsets, toff, task_c, task_j0, C);

        const int nblocks = (TMAX + 3) / 4;
        mb_task_kernel<<<dim3(nblocks), dim3(256), 0, stream>>>(
            query, mkeys, mvals, qscores, topk, counts, offsets, bucket,
            task_c, task_j0, nt, out_ret, out_w);
    } else {
        mb_generic_kernel<<<dim3(B), dim3(64), 0, stream>>>(
            query, labels, mkeys, mvals, qscores, topk, out_ret, out_w, B, n4);
    }
}